// Round 5
// baseline (329.795 us; speedup 1.0000x reference)
//
#include <hip/hip_runtime.h>

#define NQ 18
#define QDIM (1 << NQ)      // 262144
#define NB 8
#define NL 4
#define NBLK 512

typedef unsigned long long u64;

// tan-form butterfly: a' = a - i t b ; b' = b - i t a (cos^k deferred)
__device__ __forceinline__ void tbfly(float2& a, float2& b, float t) {
  float nax = fmaf(t, b.y, a.x);
  float nay = fmaf(-t, b.x, a.y);
  float nbx = fmaf(t, a.y, b.x);
  float nby = fmaf(-t, a.x, b.y);
  a = make_float2(nax, nay); b = make_float2(nbx, nby);
}
__device__ __forceinline__ void tstage(float2* v, int m, float t) {
#pragma unroll
  for (int i = 0; i < 16; ++i)
    if (!(i & m)) tbfly(v[i], v[i | m], t);
}
__device__ __forceinline__ void mix4(float2* v, float t) {
  tstage(v, 1, t); tstage(v, 2, t); tstage(v, 4, t); tstage(v, 8, t);
}
__device__ __forceinline__ void pmul(float2& a, float2 p) {
  a = make_float2(a.x * p.x - a.y * p.y, a.x * p.y + a.y * p.x);
}
// LDS swizzle: XOR 16B-granule index (byte bits 4-6) with bits 7-9. Involution.
__device__ __forceinline__ int swz(int byte) { return byte ^ (((byte >> 7) & 7) << 4); }

__device__ __forceinline__ void build_ptab(float2* ptab, float scale, int tid) {
  if (tid < 160) {
    float ss, cc; sincosf((float)tid, &ss, &cc);
    ptab[tid] = make_float2(cc * scale, -ss * scale);
  }
}

// software grid barrier; all NBLK blocks guaranteed resident (2 blk/CU max need)
__device__ __forceinline__ void gridbar(unsigned* bar, int phase) {
  __syncthreads();
  if (threadIdx.x == 0) {
    __threadfence();
    unsigned prev = __hip_atomic_fetch_add(bar + phase, 1u, __ATOMIC_ACQ_REL,
                                           __HIP_MEMORY_SCOPE_AGENT);
    if (prev == (unsigned)(NBLK - 1)) {
      __hip_atomic_store(bar + 8 + phase, 1u, __ATOMIC_RELEASE,
                         __HIP_MEMORY_SCOPE_AGENT);
    } else {
      int guard = 0;
      while (__hip_atomic_load(bar + 8 + phase, __ATOMIC_RELAXED,
                               __HIP_MEMORY_SCOPE_AGENT) == 0u) {
        __builtin_amdgcn_s_sleep(1);
        if (++guard > (1 << 22)) break;  // hang guard (~0.3s); should never trip
      }
    }
    __threadfence();
  }
  __syncthreads();
}

// ---------------- low body: element bits 0..11 ----------------
// p0: le = tid<<4 | j ; p1: le = hi4<<8 | j<<4 | lo4 ; p2: le = j<<8 | tid
template <int MODE>
__device__ __forceinline__
void low_body(const int tid, const int b, const int blk6,
              const float tf0, const float tf1, const float escale,
              float2* __restrict__ swapb, const float2* __restrict__ ptab,
              const unsigned* __restrict__ smask, const unsigned* __restrict__ sfull,
              const int* __restrict__ sdeg, float* __restrict__ wsum,
              unsigned char* __restrict__ hp8, float2* __restrict__ state,
              float* __restrict__ out) {
  const size_t bb = (size_t)b << NQ;
  const int lbase = blk6 << 12;
  const int hi4 = tid >> 4, lo4 = tid & 15;
  char* L = (char*)swapb;
  float2 v[16];

  if (MODE == 0) {
    // hp via gray code over element bits 0-3
    unsigned d = (unsigned)(lbase | (tid << 4));
    int hp = 0;
#pragma unroll
    for (int uq = 0; uq < NQ; ++uq) {
      const unsigned f = (d >> (17 - uq)) & 1u;
      hp += __popc(smask[uq] & (d ^ (0u - f)));
    }
    u64 plo = (u64)hp, phi = 0;
    int j = 0;
#pragma unroll
    for (int i = 1; i < 16; ++i) {
      const int p = __ffs(i) - 1;
      const int old = (int)((d >> p) & 1u);
      const int nb1 = __popc(sfull[p] & d);
      hp += old ? (2 * nb1 - sdeg[p]) : (sdeg[p] - 2 * nb1);
      d ^= 1u << p; j ^= 1 << p;
      if (j < 8) plo |= (u64)hp << (8 * j);
      else       phi |= (u64)hp << (8 * (j - 8));
    }
    uint4 hq;
    hq.x = (unsigned)plo; hq.y = (unsigned)(plo >> 32);
    hq.z = (unsigned)phi; hq.w = (unsigned)(phi >> 32);
    *(uint4*)(hp8 + bb + (size_t)(lbase + (tid << 4))) = hq;
#pragma unroll
    for (int jj = 0; jj < 16; ++jj) {
      const int h = (jj < 8) ? (int)((plo >> (8 * jj)) & 255)
                             : (int)((phi >> (8 * (jj - 8))) & 255);
      v[jj] = ptab[h];
    }
    mix4(v, tf0);                                 // bits 0-3
#pragma unroll
    for (int q = 0; q < 8; ++q)
      *(float4*)(L + swz((tid << 7) + (q << 4))) =
          make_float4(v[2*q].x, v[2*q].y, v[2*q+1].x, v[2*q+1].y);
    __syncthreads();
#pragma unroll
    for (int jj = 0; jj < 16; ++jj)
      v[jj] = *(const float2*)(L + swz((hi4 << 11) + (jj << 7) + (lo4 << 3)));
    mix4(v, tf0);                                 // bits 4-7
#pragma unroll
    for (int jj = 0; jj < 16; ++jj)
      *(float2*)(L + swz((hi4 << 11) + (jj << 7) + (lo4 << 3))) = v[jj];
    __syncthreads();
#pragma unroll
    for (int jj = 0; jj < 16; ++jj)
      v[jj] = *(const float2*)(L + swz((jj << 11) + (tid << 3)));
    mix4(v, tf0);                                 // bits 8-11
#pragma unroll
    for (int jj = 0; jj < 16; ++jj)
      state[bb + (size_t)(lbase + (jj << 8) + tid)] = v[jj];
    return;
  }

  // MODE 1 / 2: load at p2, mix(t0) p2 -> p1 -> p0
#pragma unroll
  for (int jj = 0; jj < 16; ++jj)
    v[jj] = state[bb + (size_t)(lbase + (jj << 8) + tid)];
  mix4(v, tf0);                                   // bits 8-11
#pragma unroll
  for (int jj = 0; jj < 16; ++jj)
    *(float2*)(L + swz((jj << 11) + (tid << 3))) = v[jj];
  __syncthreads();
#pragma unroll
  for (int jj = 0; jj < 16; ++jj)
    v[jj] = *(const float2*)(L + swz((hi4 << 11) + (jj << 7) + (lo4 << 3)));
  mix4(v, tf0);                                   // bits 4-7
#pragma unroll
  for (int jj = 0; jj < 16; ++jj)
    *(float2*)(L + swz((hi4 << 11) + (jj << 7) + (lo4 << 3))) = v[jj];
  __syncthreads();
#pragma unroll
  for (int q = 0; q < 8; ++q) {
    const float4 f = *(const float4*)(L + swz((tid << 7) + (q << 4)));
    v[2*q]   = make_float2(f.x, f.y);
    v[2*q+1] = make_float2(f.z, f.w);
  }
  mix4(v, tf0);                                   // bits 0-3

  const uint4 hq = *(const uint4*)(hp8 + bb + (size_t)(lbase + (tid << 4)));

  if (MODE == 1) {
#pragma unroll
    for (int jj = 0; jj < 16; ++jj) {
      const unsigned word = (jj < 8) ? ((jj < 4) ? hq.x : hq.y)
                                     : ((jj < 12) ? hq.z : hq.w);
      const int h = (int)((word >> ((jj & 3) * 8)) & 255u);
      pmul(v[jj], ptab[h]);
    }
    mix4(v, tf1);                                 // bits 0-3
#pragma unroll
    for (int q = 0; q < 8; ++q)
      *(float4*)(L + swz((tid << 7) + (q << 4))) =
          make_float4(v[2*q].x, v[2*q].y, v[2*q+1].x, v[2*q+1].y);
    __syncthreads();
#pragma unroll
    for (int jj = 0; jj < 16; ++jj)
      v[jj] = *(const float2*)(L + swz((hi4 << 11) + (jj << 7) + (lo4 << 3)));
    mix4(v, tf1);                                 // bits 4-7
#pragma unroll
    for (int jj = 0; jj < 16; ++jj)
      *(float2*)(L + swz((hi4 << 11) + (jj << 7) + (lo4 << 3))) = v[jj];
    __syncthreads();
#pragma unroll
    for (int jj = 0; jj < 16; ++jj)
      v[jj] = *(const float2*)(L + swz((jj << 11) + (tid << 3)));
    mix4(v, tf1);                                 // bits 8-11
#pragma unroll
    for (int jj = 0; jj < 16; ++jj)
      state[bb + (size_t)(lbase + (jj << 8) + tid)] = v[jj];
  } else {  // MODE 2: energy; scale before squaring
    float acc = 0.f;
#pragma unroll
    for (int jj = 0; jj < 16; ++jj) {
      const unsigned word = (jj < 8) ? ((jj < 4) ? hq.x : hq.y)
                                     : ((jj < 12) ? hq.z : hq.w);
      const float h = (float)((word >> ((jj & 3) * 8)) & 255u);
      const float wx = v[jj].x * escale, wy = v[jj].y * escale;
      acc = fmaf(wx * wx + wy * wy, h, acc);
    }
#pragma unroll
    for (int m = 1; m <= 32; m <<= 1) acc += __shfl_xor(acc, m, 64);
    if ((tid & 63) == 0) wsum[tid >> 6] = acc;
    __syncthreads();
    if (tid == 0) atomicAdd(out + b, wsum[0] + wsum[1] + wsum[2] + wsum[3]);
  }
}

// ---------------- high body: element bits 12..17 ----------------
__device__ __forceinline__
void high_body(const int tid, const int b, const int mid,
               const float tf0, const float tf1,
               float2* __restrict__ swapb, const float2* __restrict__ ptab,
               const unsigned char* __restrict__ hp8, float2* __restrict__ state) {
  const int w2 = tid >> 6, lane = tid & 63;
  const size_t bb = (size_t)b << NQ;
  const int base = (mid << 6) | lane;
  float2 v[16];

#pragma unroll
  for (int j = 0; j < 16; ++j)
    v[j] = state[bb + ((size_t)(((w2 << 4) | j)) << 12) + base];
  mix4(v, tf0);                                   // bits 12-15
#pragma unroll
  for (int j = 0; j < 16; ++j)
    swapb[((((w2 << 4) | j)) << 6) | lane] = v[j];
  __syncthreads();
#pragma unroll
  for (int j = 0; j < 16; ++j)
    v[j] = swapb[((((j << 2) | w2)) << 6) | lane];
  tstage(v, 4, tf0); tstage(v, 8, tf0);           // bits 16-17
#pragma unroll
  for (int j = 0; j < 16; ++j) {
    const int h = hp8[bb + ((size_t)(((j << 2) | w2)) << 12) + base];
    pmul(v[j], ptab[h]);
  }
  tstage(v, 4, tf1); tstage(v, 8, tf1);           // bits 16-17
#pragma unroll
  for (int j = 0; j < 16; ++j)
    swapb[((((j << 2) | w2)) << 6) | lane] = v[j];
  __syncthreads();
#pragma unroll
  for (int j = 0; j < 16; ++j)
    v[j] = swapb[((((w2 << 4) | j)) << 6) | lane];
  mix4(v, tf1);                                   // bits 12-15
#pragma unroll
  for (int j = 0; j < 16; ++j)
    state[bb + ((size_t)(((w2 << 4) | j)) << 12) + base] = v[j];
}

__global__ void k_init(unsigned* __restrict__ bar) {
  if (threadIdx.x < 16)
    __hip_atomic_store(bar + threadIdx.x, 0u, __ATOMIC_RELEASE,
                       __HIP_MEMORY_SCOPE_AGENT);
}

__global__ __launch_bounds__(256)
void k_fused(const float* __restrict__ betas, const float* __restrict__ adj,
             unsigned char* __restrict__ hp8, float2* __restrict__ state,
             float* __restrict__ out, unsigned* __restrict__ bar) {
  __shared__ float2 swapb[4096];   // 32 KB
  __shared__ float2 ptab[160];
  __shared__ unsigned smask[NQ];
  __shared__ unsigned sfull[4];
  __shared__ int sdeg[4];
  __shared__ float wsum[4];

  const int tid = threadIdx.x;
  const int b = blockIdx.x >> 6;
  const int idx6 = blockIdx.x & 63;

  // per-layer trig, once
  float tf[4], cp6[4], cp12[4];
#pragma unroll
  for (int t = 0; t < 4; ++t) {
    float s, c; sincosf(betas[b * NL + t], &s, &c);
    tf[t] = s / c;
    const float c2 = c * c;
    cp6[t] = c2 * c2 * c2;
    cp12[t] = cp6[t] * cp6[t];
  }

  // ---- phase 0: D1 + L0 ----
  if (tid < NQ) {
    unsigned m = 0;
    const float* row = adj + ((size_t)b * NQ + tid) * NQ;
    for (int vq = tid + 1; vq < NQ; ++vq)
      if (row[vq] > 0.5f) m |= 1u << (NQ - 1 - vq);
    smask[tid] = m;
  }
  build_ptab(ptab, 0.001953125f * cp12[0], tid);
  if (idx6 == 0 && tid == 0)
    __hip_atomic_store(out + b, 0.f, __ATOMIC_RELAXED, __HIP_MEMORY_SCOPE_AGENT);
  __syncthreads();
  if (tid < 4) {  // full neighbor masks of the 4 low element bits
    unsigned fm = smask[17 - tid];
    for (int uq = 0; uq < NQ; ++uq)
      if ((smask[uq] >> tid) & 1u) fm |= 1u << (17 - uq);
    sfull[tid] = fm; sdeg[tid] = __popc(fm);
  }
  __syncthreads();
  low_body<0>(tid, b, idx6, tf[0], 0.f, 0.f, swapb, ptab, smask, sfull, sdeg,
              wsum, hp8, state, out);
  gridbar(bar, 0);

  // ---- phase 1: H0 D2 H1 ----
  build_ptab(ptab, cp6[0] * cp6[1], tid);
  __syncthreads();
  high_body(tid, b, idx6, tf[0], tf[1], swapb, ptab, hp8, state);
  gridbar(bar, 1);

  // ---- phase 2: L1 D3 L2 ----
  build_ptab(ptab, cp12[1] * cp12[2], tid);
  __syncthreads();
  low_body<1>(tid, b, idx6, tf[1], tf[2], 0.f, swapb, ptab, smask, sfull, sdeg,
              wsum, hp8, state, out);
  gridbar(bar, 2);

  // ---- phase 3: H2 D4 H3 ----
  build_ptab(ptab, cp6[2] * cp6[3], tid);
  __syncthreads();
  high_body(tid, b, idx6, tf[2], tf[3], swapb, ptab, hp8, state);
  gridbar(bar, 3);

  // ---- phase 4: L3 + E ----
  low_body<2>(tid, b, idx6, tf[3], 0.f, cp12[3], swapb, ptab, smask, sfull,
              sdeg, wsum, hp8, state, out);
}

extern "C" void kernel_launch(void* const* d_in, const int* in_sizes, int n_in,
                              void* d_out, int out_size, void* d_ws, size_t ws_size,
                              hipStream_t stream) {
  const float* betas = (const float*)d_in[0];  // [8][4]
  const float* adj   = (const float*)d_in[1];  // [8][18][18]
  float* out = (float*)d_out;                  // [8] float32
  char* ws = (char*)d_ws;
  float2* state = (float2*)ws;                                                   // 16 MB
  unsigned char* hp8 = (unsigned char*)(ws + (size_t)NB * QDIM * sizeof(float2)); // 2 MB
  unsigned* bar = (unsigned*)(ws + (size_t)NB * QDIM * (sizeof(float2) + 1));    // 64 B

  k_init<<<1, 64, 0, stream>>>(bar);  // stream-ordered before k_fused
  k_fused<<<NBLK, 256, 0, stream>>>(betas, adj, hp8, state, out, bar);
}

// Round 6
// 54.286 us; speedup vs baseline: 6.0752x; 6.0752x over previous
//
#include <hip/hip_runtime.h>
#include <hip/hip_fp16.h>

#define NQ 18
#define QDIM (1 << NQ)      // 262144
#define NB 8
#define NL 4

typedef unsigned u32;
typedef unsigned long long u64;

// tan-form butterfly: a' = a - i t b ; b' = b - i t a (cos^k deferred into ptab)
__device__ __forceinline__ void tbfly(float2& a, float2& b, float t) {
  float nax = fmaf(t, b.y, a.x);
  float nay = fmaf(-t, b.x, a.y);
  float nbx = fmaf(t, a.y, b.x);
  float nby = fmaf(-t, a.x, b.y);
  a = make_float2(nax, nay); b = make_float2(nbx, nby);
}
__device__ __forceinline__ void tstage(float2* v, int m, float t) {
#pragma unroll
  for (int i = 0; i < 16; ++i)
    if (!(i & m)) tbfly(v[i], v[i | m], t);
}
__device__ __forceinline__ void mix4(float2* v, float t) {
  tstage(v, 1, t); tstage(v, 2, t); tstage(v, 4, t); tstage(v, 8, t);
}
__device__ __forceinline__ void pmul(float2& a, float2 p) {
  a = make_float2(a.x * p.x - a.y * p.y, a.x * p.y + a.y * p.x);
}
// LDS swizzle (same as round 4): XOR 16B-granule bits 4-6 with bits 7-9.
__device__ __forceinline__ int swz(int byte) { return byte ^ (((byte >> 7) & 7) << 4); }

// fp16 pack/unpack: one complex = half2 in a u32
__device__ __forceinline__ float2 h2f(u32 u) {
  __half2 h; *(u32*)&h = u; return __half22float2(h);
}
__device__ __forceinline__ u32 f2h(float2 f) {
  __half2 h = __float22half2_rn(f); return *(u32*)&h;
}

// ---------------- low pass: element bits 0..11 ----------------
// Partitions (reg-bit sets), same LDS addresses as round 4:
//  p0: le = tid<<4 | j   (regs = bits 0-3)   <- global state I/O (uint4, 64B/thread)
//  p1: le = hi4<<8 | j<<4 | lo4 (regs = 4-7)
//  p2: le = j<<8 | tid   (regs = bits 8-11)  <- diagonal (hp bytes lane-consecutive)
// MODE 0: hp gray-code @p2, init, mix(t0) p2->p1->p0, store @p0
// MODE 1: load @p0, mix(t0) p0->p1->p2, D @p2, mix(t1) p2->p1->p0, store @p0
// MODE 2: load @p0, mix(t0) p0->p1->p2, energy @p2 -> atomicAdd
template <int MODE>
__global__ __launch_bounds__(256)
void k_low(const float* __restrict__ betas, const float* __restrict__ adj,
           unsigned char* __restrict__ hp8, u32* __restrict__ state,
           float* __restrict__ out, int t0) {
  __shared__ float2 swapb[4096];   // 32 KB, f32 precision for transposes
  __shared__ float2 ptab[160];
  __shared__ unsigned smask[NQ];
  __shared__ unsigned sfull[4];
  __shared__ int sdeg[4];
  __shared__ float wsum[4];

  const int tid = threadIdx.x;
  const int b = blockIdx.x >> 6;
  const int blk6 = blockIdx.x & 63;
  const size_t bb = (size_t)b << NQ;
  const int lbase = blk6 << 12;
  const int hi4 = tid >> 4, lo4 = tid & 15;
  char* L = (char*)swapb;

  const float beta0 = betas[b * NL + t0];
  float s0, c0; sincosf(beta0, &s0, &c0);
  const float tf0 = s0 / c0;
  const float c0p2 = c0 * c0, c0p4 = c0p2 * c0p2;
  const float c0p12 = c0p4 * c0p4 * c0p4;

  float tf1 = 0.f, scale = 1.f;
  if (MODE == 0) scale = 0.001953125f * c0p12;   // 1/sqrt(2^18) * cos^12
  if (MODE == 1) {
    const float beta1 = betas[b * NL + t0 + 1];
    float s1, c1; sincosf(beta1, &s1, &c1);
    tf1 = s1 / c1;
    const float c1p2 = c1 * c1, c1p4 = c1p2 * c1p2;
    scale = c0p12 * (c1p4 * c1p4 * c1p4);
  }

  if (MODE == 0) {
    if (tid < NQ) {
      unsigned m = 0;
      const float* row = adj + ((size_t)b * NQ + tid) * NQ;
      for (int vq = tid + 1; vq < NQ; ++vq)
        if (row[vq] > 0.5f) m |= 1u << (NQ - 1 - vq);
      smask[tid] = m;
    }
    if (blk6 == 0 && tid == 0) out[b] = 0.f;  // P1 completes before P5 launches
    __syncthreads();
    if (tid < 4) {  // full neighbor masks for element bits 8-11 (qubit 9-p)
      const int p = tid;
      unsigned fm = smask[9 - p];
      for (int uq = 0; uq < NQ; ++uq)
        if ((smask[uq] >> (8 + p)) & 1u) fm |= 1u << (17 - uq);
      sfull[p] = fm; sdeg[p] = __popc(fm);
    }
  }
  if (MODE != 2 && tid < 160) {
    float ss, cc; sincosf((float)tid, &ss, &cc);
    ptab[tid] = make_float2(cc * scale, -ss * scale);  // e^{-i h} * scale
  }

  float2 v[16];
  const size_t gb = bb + (size_t)(lbase + tid);   // p2 base: +jj<<8

  if (MODE == 0) {
    __syncthreads();
    // hp via gray code over element bits 8-11 (p2 regs)
    unsigned d = (unsigned)(lbase | tid);
    int hp = 0;
#pragma unroll
    for (int uq = 0; uq < NQ; ++uq) {
      const unsigned f = (d >> (17 - uq)) & 1u;
      hp += __popc(smask[uq] & (d ^ (0u - f)));
    }
    u64 plo = (u64)hp, phi = 0;
    int j = 0;
#pragma unroll
    for (int i = 1; i < 16; ++i) {
      const int p = __ffs(i) - 1;
      const int old = (int)((d >> (8 + p)) & 1u);
      const int nb1 = __popc(sfull[p] & d);
      hp += old ? (2 * nb1 - sdeg[p]) : (sdeg[p] - 2 * nb1);
      d ^= 1u << (8 + p); j ^= 1 << p;
      if (j < 8) plo |= (u64)hp << (8 * j);
      else       phi |= (u64)hp << (8 * (j - 8));
    }
#pragma unroll
    for (int jj = 0; jj < 16; ++jj) {
      const int h = (jj < 8) ? (int)((plo >> (8 * jj)) & 255)
                             : (int)((phi >> (8 * (jj - 8))) & 255);
      hp8[gb + (jj << 8)] = (unsigned char)h;   // lane-consecutive 64B stores
      v[jj] = ptab[h];
    }
    mix4(v, tf0);                                 // bits 8-11 @p2
#pragma unroll
    for (int jj = 0; jj < 16; ++jj)
      *(float2*)(L + swz((jj << 11) + (tid << 3))) = v[jj];
    __syncthreads();
#pragma unroll
    for (int jj = 0; jj < 16; ++jj)
      v[jj] = *(const float2*)(L + swz((hi4 << 11) + (jj << 7) + (lo4 << 3)));
    mix4(v, tf0);                                 // bits 4-7 @p1
#pragma unroll
    for (int jj = 0; jj < 16; ++jj)
      *(float2*)(L + swz((hi4 << 11) + (jj << 7) + (lo4 << 3))) = v[jj];
    __syncthreads();
#pragma unroll
    for (int q = 0; q < 8; ++q) {
      const float4 f = *(const float4*)(L + swz((tid << 7) + (q << 4)));
      v[2*q]   = make_float2(f.x, f.y);
      v[2*q+1] = make_float2(f.z, f.w);
    }
    mix4(v, tf0);                                 // bits 0-3 @p0
    uint4* gdst = (uint4*)(state + bb + lbase + (tid << 4));
#pragma unroll
    for (int q = 0; q < 4; ++q) {
      uint4 w;
      w.x = f2h(v[4*q]); w.y = f2h(v[4*q+1]); w.z = f2h(v[4*q+2]); w.w = f2h(v[4*q+3]);
      gdst[q] = w;
    }
    return;
  }

  // MODE 1 / 2: load @p0 (vectorized), mix(t0) p0 -> p1 -> p2
  const uint4* gsrc = (const uint4*)(state + bb + lbase + (tid << 4));
#pragma unroll
  for (int q = 0; q < 4; ++q) {
    const uint4 w = gsrc[q];
    v[4*q]   = h2f(w.x); v[4*q+1] = h2f(w.y);
    v[4*q+2] = h2f(w.z); v[4*q+3] = h2f(w.w);
  }
  mix4(v, tf0);                                   // bits 0-3 @p0
#pragma unroll
  for (int q = 0; q < 8; ++q)
    *(float4*)(L + swz((tid << 7) + (q << 4))) =
        make_float4(v[2*q].x, v[2*q].y, v[2*q+1].x, v[2*q+1].y);
  __syncthreads();
#pragma unroll
  for (int jj = 0; jj < 16; ++jj)
    v[jj] = *(const float2*)(L + swz((hi4 << 11) + (jj << 7) + (lo4 << 3)));
  mix4(v, tf0);                                   // bits 4-7 @p1
#pragma unroll
  for (int jj = 0; jj < 16; ++jj)
    *(float2*)(L + swz((hi4 << 11) + (jj << 7) + (lo4 << 3))) = v[jj];
  __syncthreads();
#pragma unroll
  for (int jj = 0; jj < 16; ++jj)
    v[jj] = *(const float2*)(L + swz((jj << 11) + (tid << 3)));
  mix4(v, tf0);                                   // bits 8-11 @p2

  if (MODE == 1) {
#pragma unroll
    for (int jj = 0; jj < 16; ++jj)
      pmul(v[jj], ptab[hp8[gb + (jj << 8)]]);     // coalesced byte loads
    mix4(v, tf1);                                 // bits 8-11 @p2
#pragma unroll
    for (int jj = 0; jj < 16; ++jj)
      *(float2*)(L + swz((jj << 11) + (tid << 3))) = v[jj];
    __syncthreads();
#pragma unroll
    for (int jj = 0; jj < 16; ++jj)
      v[jj] = *(const float2*)(L + swz((hi4 << 11) + (jj << 7) + (lo4 << 3)));
    mix4(v, tf1);                                 // bits 4-7 @p1
#pragma unroll
    for (int jj = 0; jj < 16; ++jj)
      *(float2*)(L + swz((hi4 << 11) + (jj << 7) + (lo4 << 3))) = v[jj];
    __syncthreads();
#pragma unroll
    for (int q = 0; q < 8; ++q) {
      const float4 f = *(const float4*)(L + swz((tid << 7) + (q << 4)));
      v[2*q]   = make_float2(f.x, f.y);
      v[2*q+1] = make_float2(f.z, f.w);
    }
    mix4(v, tf1);                                 // bits 0-3 @p0
    uint4* gdst = (uint4*)(state + bb + lbase + (tid << 4));
#pragma unroll
    for (int q = 0; q < 4; ++q) {
      uint4 w;
      w.x = f2h(v[4*q]); w.y = f2h(v[4*q+1]); w.z = f2h(v[4*q+2]); w.w = f2h(v[4*q+3]);
      gdst[q] = w;
    }
  } else {  // MODE 2: energy; scale before squaring
    float acc = 0.f;
#pragma unroll
    for (int jj = 0; jj < 16; ++jj) {
      const float h = (float)hp8[gb + (jj << 8)];
      const float wx = v[jj].x * c0p12, wy = v[jj].y * c0p12;
      acc = fmaf(wx * wx + wy * wy, h, acc);
    }
#pragma unroll
    for (int m = 1; m <= 32; m <<= 1) acc += __shfl_xor(acc, m, 64);
    if ((tid & 63) == 0) wsum[tid >> 6] = acc;
    __syncthreads();
    if (tid == 0) atomicAdd(out + b, wsum[0] + wsum[1] + wsum[2] + wsum[3]);
  }
}

// ---------------- high pass: element bits 12..17 ----------------
// 256 thr: w2 = tid>>6, lane = cols (bits 0-5), mid = blockIdx&63 (bits 6-11).
// p0 rows = w2<<4|j (j = bits 12-15); p1 rows = j<<2|w2 (stages 16-17 = masks 4,8).
// [H_t0, D, H_t1]
__global__ __launch_bounds__(256)
void k_high(const float* __restrict__ betas, const unsigned char* __restrict__ hp8,
            u32* __restrict__ state, int t0) {
  __shared__ float2 swapb[4096];
  __shared__ float2 ptab[160];
  const int tid = threadIdx.x;
  const int w2 = tid >> 6, lane = tid & 63;
  const int b = blockIdx.x >> 6, mid = blockIdx.x & 63;
  const size_t bb = (size_t)b << NQ;
  const int base = (mid << 6) | lane;

  const float beta0 = betas[b * NL + t0], beta1 = betas[b * NL + t0 + 1];
  float s0, c0, s1, c1;
  sincosf(beta0, &s0, &c0); sincosf(beta1, &s1, &c1);
  const float tf0 = s0 / c0, tf1 = s1 / c1;
  const float c0p2 = c0 * c0, c1p2 = c1 * c1;
  const float scale = (c0p2 * c0p2 * c0p2) * (c1p2 * c1p2 * c1p2);  // cos^6 each
  if (tid < 160) {
    float ss, cc; sincosf((float)tid, &ss, &cc);
    ptab[tid] = make_float2(cc * scale, -ss * scale);
  }

  float2 v[16];
#pragma unroll
  for (int j = 0; j < 16; ++j)
    v[j] = h2f(state[bb + ((size_t)((w2 << 4) | j) << 12) + base]);
  mix4(v, tf0);                                   // bits 12-15
#pragma unroll
  for (int j = 0; j < 16; ++j)
    swapb[(((w2 << 4) | j) << 6) | lane] = v[j];
  __syncthreads();
#pragma unroll
  for (int j = 0; j < 16; ++j)
    v[j] = swapb[(((j << 2) | w2) << 6) | lane];
  tstage(v, 4, tf0); tstage(v, 8, tf0);           // bits 16-17
#pragma unroll
  for (int j = 0; j < 16; ++j) {
    const int h = hp8[bb + ((size_t)((j << 2) | w2) << 12) + base];
    pmul(v[j], ptab[h]);
  }
  tstage(v, 4, tf1); tstage(v, 8, tf1);           // bits 16-17
#pragma unroll
  for (int j = 0; j < 16; ++j)
    swapb[(((j << 2) | w2) << 6) | lane] = v[j];
  __syncthreads();
#pragma unroll
  for (int j = 0; j < 16; ++j)
    v[j] = swapb[(((w2 << 4) | j) << 6) | lane];
  mix4(v, tf1);                                   // bits 12-15
#pragma unroll
  for (int j = 0; j < 16; ++j)
    state[bb + ((size_t)((w2 << 4) | j) << 12) + base] = f2h(v[j]);
}

extern "C" void kernel_launch(void* const* d_in, const int* in_sizes, int n_in,
                              void* d_out, int out_size, void* d_ws, size_t ws_size,
                              hipStream_t stream) {
  const float* betas = (const float*)d_in[0];  // [8][4]
  const float* adj   = (const float*)d_in[1];  // [8][18][18]
  float* out = (float*)d_out;                  // [8] float32
  char* ws = (char*)d_ws;
  u32* state = (u32*)ws;                                              // 8 MB (half2)
  unsigned char* hp8 = (unsigned char*)(ws + (size_t)NB * QDIM * 4);  // 2 MB

  dim3 grid(NB * 64), blk(256);
  // P1: D + L0      P2: H0 D H1      P3: L1 D L2      P4: H2 D H3      P5: L3 + E
  k_low<0><<<grid, blk, 0, stream>>>(betas, adj, hp8, state, out, 0);
  k_high  <<<grid, blk, 0, stream>>>(betas, hp8, state, 0);
  k_low<1><<<grid, blk, 0, stream>>>(betas, adj, hp8, state, out, 1);
  k_high  <<<grid, blk, 0, stream>>>(betas, hp8, state, 2);
  k_low<2><<<grid, blk, 0, stream>>>(betas, adj, hp8, state, out, 3);
}

// Round 7
// 53.926 us; speedup vs baseline: 6.1157x; 1.0067x over previous
//
#include <hip/hip_runtime.h>
#include <hip/hip_fp16.h>

#define NQ 18
#define QDIM (1 << NQ)      // 262144
#define NB 8
#define NL 4

typedef unsigned u32;
typedef unsigned long long u64;

#define DPP_XOR1 0xB1   // quad_perm [1,0,3,2]
#define DPP_XOR2 0x4E   // quad_perm [2,3,0,1]

// tan-form butterfly: a' = a - i t b ; b' = b - i t a (cos^k deferred into ptab)
__device__ __forceinline__ void tbfly(float2& a, float2& b, float t) {
  float nax = fmaf(t, b.y, a.x);
  float nay = fmaf(-t, b.x, a.y);
  float nbx = fmaf(t, a.y, b.x);
  float nby = fmaf(-t, a.x, b.y);
  a = make_float2(nax, nay); b = make_float2(nbx, nby);
}
__device__ __forceinline__ void tstage(float2* v, int m, float t) {
#pragma unroll
  for (int i = 0; i < 16; ++i)
    if (!(i & m)) tbfly(v[i], v[i | m], t);
}
// cross-lane butterfly via DPP (VALU pipe, no LDS traffic); same symmetric
// form as the old shfl stage: new = mine + t*(other.y, -other.x)
template <int CTRL>
__device__ __forceinline__ void dppstage(float2* v, float t) {
#pragma unroll
  for (int k = 0; k < 16; ++k) {
    float ox = __int_as_float(
        __builtin_amdgcn_mov_dpp(__float_as_int(v[k].x), CTRL, 0xF, 0xF, true));
    float oy = __int_as_float(
        __builtin_amdgcn_mov_dpp(__float_as_int(v[k].y), CTRL, 0xF, 0xF, true));
    v[k] = make_float2(fmaf(t, oy, v[k].x), fmaf(-t, ox, v[k].y));
  }
}
// partition A mix: elem bits 0-3 (reg) + 4,5 (lane 0,1 via dpp)
__device__ __forceinline__ void mixA(float2* v, float t) {
  tstage(v, 1, t); tstage(v, 2, t); tstage(v, 4, t); tstage(v, 8, t);
  dppstage<DPP_XOR1>(v, t); dppstage<DPP_XOR2>(v, t);
}
// partition B mix: elem bits 8-11 (reg) + 6,7 (lane 0,1 via dpp)
__device__ __forceinline__ void mixB(float2* v, float t) {
  tstage(v, 1, t); tstage(v, 2, t); tstage(v, 4, t); tstage(v, 8, t);
  dppstage<DPP_XOR1>(v, t); dppstage<DPP_XOR2>(v, t);
}
__device__ __forceinline__ void pmul(float2& a, float2 p) {
  a = make_float2(a.x * p.x - a.y * p.y, a.x * p.y + a.y * p.x);
}
// LDS swizzle: XOR 16B-granule bits 4-6 with bits 7-9. Involution, both sides.
__device__ __forceinline__ int swz(int byte) { return byte ^ (((byte >> 7) & 7) << 4); }

// fp16 pack/unpack: one complex = half2 in a u32
__device__ __forceinline__ float2 h2f(u32 u) {
  __half2 h; *(u32*)&h = u; return __half22float2(h);
}
__device__ __forceinline__ u32 f2h(float2 f) {
  __half2 h = __float22half2_rn(f); return *(u32*)&h;
}

// ---------------- low pass: element bits 0..11 ----------------
// 256 thr, 16 elems/thread, tile = 4096 consecutive elems.
//  A: le = tid<<4 | j          (reg j = bits 0-3; lane0,1 = bits 4,5) <- global I/O
//  B: le = j<<8 | (l&3)<<6 | w<<4 | (l>>2)   (reg j = bits 8-11; lane0,1 = bits 6,7)
// ONE LDS transpose covers a full 12-bit mix (A: 0-5, B: 6-11).
// MODE 0: gray-code hp @A, init, mixA(t0), swap, mixB(t0), swap, store @A
// MODE 1: load @A, mixA(t0), swap, mixB(t0), D @B, mixB(t1), swap, mixA(t1), store
// MODE 2: load @A, mixA(t0), swap, mixB(t0), energy @B -> atomicAdd
template <int MODE>
__global__ __launch_bounds__(256)
void k_low(const float* __restrict__ betas, const float* __restrict__ adj,
           unsigned char* __restrict__ hp8, u32* __restrict__ state,
           float* __restrict__ out, int t0) {
  __shared__ float2 swapb[4096];   // 32 KB
  __shared__ float2 ptab[160];
  __shared__ unsigned smask[NQ];
  __shared__ unsigned sfull[4];
  __shared__ int sdeg[4];
  __shared__ float wsum[4];

  const int tid = threadIdx.x;
  const int l = tid & 63, w = tid >> 6;
  const int b = blockIdx.x >> 6;
  const int blk6 = blockIdx.x & 63;
  const size_t bb = (size_t)b << NQ;
  const int lbase = blk6 << 12;
  char* L = (char*)swapb;
  // B-partition: block-local elem offset (add j<<8), and LDS byte offset (add j<<11)
  const int leB = ((l & 3) << 6) | (w << 4) | ((l >> 2) & 15);
  const int bB  = leB << 3;

  const float beta0 = betas[b * NL + t0];
  float s0, c0; sincosf(beta0, &s0, &c0);
  const float tf0 = s0 / c0;
  const float c0p2 = c0 * c0, c0p4 = c0p2 * c0p2;
  const float c0p12 = c0p4 * c0p4 * c0p4;

  float tf1 = 0.f, scale = 1.f;
  if (MODE == 0) scale = 0.001953125f * c0p12;   // 1/sqrt(2^18) * cos^12
  if (MODE == 1) {
    const float beta1 = betas[b * NL + t0 + 1];
    float s1, c1; sincosf(beta1, &s1, &c1);
    tf1 = s1 / c1;
    const float c1p2 = c1 * c1, c1p4 = c1p2 * c1p2;
    scale = c0p12 * (c1p4 * c1p4 * c1p4);
  }

  if (MODE == 0) {
    if (tid < NQ) {
      unsigned m = 0;
      const float* row = adj + ((size_t)b * NQ + tid) * NQ;
      for (int vq = tid + 1; vq < NQ; ++vq)
        if (row[vq] > 0.5f) m |= 1u << (NQ - 1 - vq);
      smask[tid] = m;
    }
    if (blk6 == 0 && tid == 0) out[b] = 0.f;  // P1 completes before P5 launches
    __syncthreads();
    if (tid < 4) {  // full neighbor masks for element bits 0-3 (qubit 17-p)
      unsigned fm = smask[17 - tid];
      for (int uq = 0; uq < NQ; ++uq)
        if ((smask[uq] >> tid) & 1u) fm |= 1u << (17 - uq);
      sfull[tid] = fm; sdeg[tid] = __popc(fm);
    }
  }
  if (MODE != 2 && tid < 160) {
    float ss, cc; sincosf((float)tid, &ss, &cc);
    ptab[tid] = make_float2(cc * scale, -ss * scale);  // e^{-i h} * scale
  }

  float2 v[16];

  if (MODE == 0) {
    __syncthreads();
    // hp via gray code over element bits 0-3 (A regs)
    unsigned d = (unsigned)(lbase | (tid << 4));
    int hp = 0;
#pragma unroll
    for (int uq = 0; uq < NQ; ++uq) {
      const unsigned f = (d >> (17 - uq)) & 1u;
      hp += __popc(smask[uq] & (d ^ (0u - f)));
    }
    u64 plo = (u64)hp, phi = 0;
    int j = 0;
#pragma unroll
    for (int i = 1; i < 16; ++i) {
      const int p = __ffs(i) - 1;
      const int old = (int)((d >> p) & 1u);
      const int nb1 = __popc(sfull[p] & d);
      hp += old ? (2 * nb1 - sdeg[p]) : (sdeg[p] - 2 * nb1);
      d ^= 1u << p; j ^= 1 << p;
      if (j < 8) plo |= (u64)hp << (8 * j);
      else       phi |= (u64)hp << (8 * (j - 8));
    }
    uint4 hq;
    hq.x = (unsigned)plo; hq.y = (unsigned)(plo >> 32);
    hq.z = (unsigned)phi; hq.w = (unsigned)(phi >> 32);
    *(uint4*)(hp8 + bb + (size_t)(lbase + (tid << 4))) = hq;
#pragma unroll
    for (int jj = 0; jj < 16; ++jj) {
      const int h = (jj < 8) ? (int)((plo >> (8 * jj)) & 255)
                             : (int)((phi >> (8 * (jj - 8))) & 255);
      v[jj] = ptab[h];
    }
    mixA(v, tf0);                                 // bits 0-5
#pragma unroll
    for (int q = 0; q < 8; ++q)                   // swap A -> B
      *(float4*)(L + swz((tid << 7) + (q << 4))) =
          make_float4(v[2*q].x, v[2*q].y, v[2*q+1].x, v[2*q+1].y);
    __syncthreads();
#pragma unroll
    for (int jj = 0; jj < 16; ++jj)
      v[jj] = *(const float2*)(L + swz((jj << 11) + bB));
    mixB(v, tf0);                                 // bits 6-11
#pragma unroll
    for (int jj = 0; jj < 16; ++jj)               // swap B -> A
      *(float2*)(L + swz((jj << 11) + bB)) = v[jj];
    __syncthreads();
#pragma unroll
    for (int q = 0; q < 8; ++q) {
      const float4 f = *(const float4*)(L + swz((tid << 7) + (q << 4)));
      v[2*q]   = make_float2(f.x, f.y);
      v[2*q+1] = make_float2(f.z, f.w);
    }
    uint4* gdst = (uint4*)(state + bb + lbase + (tid << 4));
#pragma unroll
    for (int q = 0; q < 4; ++q) {
      uint4 t4;
      t4.x = f2h(v[4*q]);   t4.y = f2h(v[4*q+1]);
      t4.z = f2h(v[4*q+2]); t4.w = f2h(v[4*q+3]);
      gdst[q] = t4;
    }
    return;
  }

  // MODE 1 / 2: load @A (vectorized), mixA(t0), swap -> B, mixB(t0)
  const uint4* gsrc = (const uint4*)(state + bb + lbase + (tid << 4));
#pragma unroll
  for (int q = 0; q < 4; ++q) {
    const uint4 t4 = gsrc[q];
    v[4*q]   = h2f(t4.x); v[4*q+1] = h2f(t4.y);
    v[4*q+2] = h2f(t4.z); v[4*q+3] = h2f(t4.w);
  }
  mixA(v, tf0);                                   // bits 0-5
#pragma unroll
  for (int q = 0; q < 8; ++q)
    *(float4*)(L + swz((tid << 7) + (q << 4))) =
        make_float4(v[2*q].x, v[2*q].y, v[2*q+1].x, v[2*q+1].y);
  __syncthreads();
#pragma unroll
  for (int jj = 0; jj < 16; ++jj)
    v[jj] = *(const float2*)(L + swz((jj << 11) + bB));
  mixB(v, tf0);                                   // bits 6-11

  if (MODE == 1) {
    const unsigned char* hq = hp8 + bb + (size_t)(lbase + leB);
#pragma unroll
    for (int jj = 0; jj < 16; ++jj)
      pmul(v[jj], ptab[hq[jj << 8]]);             // diagonal @B
    mixB(v, tf1);                                 // bits 6-11
#pragma unroll
    for (int jj = 0; jj < 16; ++jj)               // swap B -> A
      *(float2*)(L + swz((jj << 11) + bB)) = v[jj];
    __syncthreads();
#pragma unroll
    for (int q = 0; q < 8; ++q) {
      const float4 f = *(const float4*)(L + swz((tid << 7) + (q << 4)));
      v[2*q]   = make_float2(f.x, f.y);
      v[2*q+1] = make_float2(f.z, f.w);
    }
    mixA(v, tf1);                                 // bits 0-5
    uint4* gdst = (uint4*)(state + bb + lbase + (tid << 4));
#pragma unroll
    for (int q = 0; q < 4; ++q) {
      uint4 t4;
      t4.x = f2h(v[4*q]);   t4.y = f2h(v[4*q+1]);
      t4.z = f2h(v[4*q+2]); t4.w = f2h(v[4*q+3]);
      gdst[q] = t4;
    }
  } else {  // MODE 2: energy @B; scale before squaring
    const unsigned char* hq = hp8 + bb + (size_t)(lbase + leB);
    float acc = 0.f;
#pragma unroll
    for (int jj = 0; jj < 16; ++jj) {
      const float h = (float)hq[jj << 8];
      const float wx = v[jj].x * c0p12, wy = v[jj].y * c0p12;
      acc = fmaf(wx * wx + wy * wy, h, acc);
    }
#pragma unroll
    for (int m = 1; m <= 32; m <<= 1) acc += __shfl_xor(acc, m, 64);
    if (l == 0) wsum[w] = acc;
    __syncthreads();
    if (tid == 0) atomicAdd(out + b, wsum[0] + wsum[1] + wsum[2] + wsum[3]);
  }
}

// ---------------- high pass: element bits 12..17 (unchanged) ----------------
__global__ __launch_bounds__(256)
void k_high(const float* __restrict__ betas, const unsigned char* __restrict__ hp8,
            u32* __restrict__ state, int t0) {
  __shared__ float2 swapb[4096];
  __shared__ float2 ptab[160];
  const int tid = threadIdx.x;
  const int w2 = tid >> 6, lane = tid & 63;
  const int b = blockIdx.x >> 6, mid = blockIdx.x & 63;
  const size_t bb = (size_t)b << NQ;
  const int base = (mid << 6) | lane;

  const float beta0 = betas[b * NL + t0], beta1 = betas[b * NL + t0 + 1];
  float s0, c0, s1, c1;
  sincosf(beta0, &s0, &c0); sincosf(beta1, &s1, &c1);
  const float tf0 = s0 / c0, tf1 = s1 / c1;
  const float c0p2 = c0 * c0, c1p2 = c1 * c1;
  const float scale = (c0p2 * c0p2 * c0p2) * (c1p2 * c1p2 * c1p2);  // cos^6 each
  if (tid < 160) {
    float ss, cc; sincosf((float)tid, &ss, &cc);
    ptab[tid] = make_float2(cc * scale, -ss * scale);
  }

  float2 v[16];
#pragma unroll
  for (int j = 0; j < 16; ++j)
    v[j] = h2f(state[bb + ((size_t)((w2 << 4) | j) << 12) + base]);
  tstage(v, 1, tf0); tstage(v, 2, tf0); tstage(v, 4, tf0); tstage(v, 8, tf0);
#pragma unroll
  for (int j = 0; j < 16; ++j)
    swapb[(((w2 << 4) | j) << 6) | lane] = v[j];
  __syncthreads();
#pragma unroll
  for (int j = 0; j < 16; ++j)
    v[j] = swapb[(((j << 2) | w2) << 6) | lane];
  tstage(v, 4, tf0); tstage(v, 8, tf0);           // bits 16-17
#pragma unroll
  for (int j = 0; j < 16; ++j) {
    const int h = hp8[bb + ((size_t)((j << 2) | w2) << 12) + base];
    pmul(v[j], ptab[h]);
  }
  tstage(v, 4, tf1); tstage(v, 8, tf1);           // bits 16-17
#pragma unroll
  for (int j = 0; j < 16; ++j)
    swapb[(((j << 2) | w2) << 6) | lane] = v[j];
  __syncthreads();
#pragma unroll
  for (int j = 0; j < 16; ++j)
    v[j] = swapb[(((w2 << 4) | j) << 6) | lane];
  tstage(v, 1, tf1); tstage(v, 2, tf1); tstage(v, 4, tf1); tstage(v, 8, tf1);
#pragma unroll
  for (int j = 0; j < 16; ++j)
    state[bb + ((size_t)((w2 << 4) | j) << 12) + base] = f2h(v[j]);
}

extern "C" void kernel_launch(void* const* d_in, const int* in_sizes, int n_in,
                              void* d_out, int out_size, void* d_ws, size_t ws_size,
                              hipStream_t stream) {
  const float* betas = (const float*)d_in[0];  // [8][4]
  const float* adj   = (const float*)d_in[1];  // [8][18][18]
  float* out = (float*)d_out;                  // [8] float32
  char* ws = (char*)d_ws;
  u32* state = (u32*)ws;                                              // 8 MB (half2)
  unsigned char* hp8 = (unsigned char*)(ws + (size_t)NB * QDIM * 4);  // 2 MB

  dim3 grid(NB * 64), blk(256);
  // P1: D + L0      P2: H0 D H1      P3: L1 D L2      P4: H2 D H3      P5: L3 + E
  k_low<0><<<grid, blk, 0, stream>>>(betas, adj, hp8, state, out, 0);
  k_high  <<<grid, blk, 0, stream>>>(betas, hp8, state, 0);
  k_low<1><<<grid, blk, 0, stream>>>(betas, adj, hp8, state, out, 1);
  k_high  <<<grid, blk, 0, stream>>>(betas, hp8, state, 2);
  k_low<2><<<grid, blk, 0, stream>>>(betas, adj, hp8, state, out, 3);
}

// Round 9
// 41.911 us; speedup vs baseline: 7.8689x; 1.2867x over previous
//
#include <hip/hip_runtime.h>
#include <hip/hip_fp16.h>

#define NQ 18
#define QDIM (1 << NQ)      // 262144
#define NB 8
#define NL 4

typedef unsigned u32;
typedef unsigned long long u64;

#define DPP_XOR1 0xB1   // quad_perm [1,0,3,2]
#define DPP_XOR2 0x4E   // quad_perm [2,3,0,1]

// tan-form butterfly: a' = a - i t b ; b' = b - i t a (cos^k deferred into ptab)
__device__ __forceinline__ void tbfly(float2& a, float2& b, float t) {
  float nax = fmaf(t, b.y, a.x);
  float nay = fmaf(-t, b.x, a.y);
  float nbx = fmaf(t, a.y, b.x);
  float nby = fmaf(-t, a.x, b.y);
  a = make_float2(nax, nay); b = make_float2(nbx, nby);
}
__device__ __forceinline__ void tstage(float2* v, int m, float t) {
#pragma unroll
  for (int i = 0; i < 16; ++i)
    if (!(i & m)) tbfly(v[i], v[i | m], t);
}
// cross-lane butterfly via DPP (VALU pipe, no LDS traffic)
template <int CTRL>
__device__ __forceinline__ void dppstage(float2* v, float t) {
#pragma unroll
  for (int k = 0; k < 16; ++k) {
    float ox = __int_as_float(
        __builtin_amdgcn_mov_dpp(__float_as_int(v[k].x), CTRL, 0xF, 0xF, true));
    float oy = __int_as_float(
        __builtin_amdgcn_mov_dpp(__float_as_int(v[k].y), CTRL, 0xF, 0xF, true));
    v[k] = make_float2(fmaf(t, oy, v[k].x), fmaf(-t, ox, v[k].y));
  }
}
// partition A mix: elem bits 0-3 (reg) + 4,5 (lane bits 0,1 via dpp)
__device__ __forceinline__ void mixA(float2* v, float t) {
  tstage(v, 1, t); tstage(v, 2, t); tstage(v, 4, t); tstage(v, 8, t);
  dppstage<DPP_XOR1>(v, t); dppstage<DPP_XOR2>(v, t);
}
// partition B mix: elem bits 8-11 (reg) + 6,7 (lane bits 0,1 via dpp)
__device__ __forceinline__ void mixB(float2* v, float t) {
  tstage(v, 1, t); tstage(v, 2, t); tstage(v, 4, t); tstage(v, 8, t);
  dppstage<DPP_XOR1>(v, t); dppstage<DPP_XOR2>(v, t);
}
__device__ __forceinline__ void pmul(float2& a, float2 p) {
  a = make_float2(a.x * p.x - a.y * p.y, a.x * p.y + a.y * p.x);
}
// LDS swizzle: XOR 16B-granule bits 4-6 with bits 7-9. Involution, both sides.
__device__ __forceinline__ int swz(int byte) { return byte ^ (((byte >> 7) & 7) << 4); }

// fp16 pack/unpack: one complex = half2 in a u32
__device__ __forceinline__ float2 h2f(u32 u) {
  __half2 h; *(u32*)&h = u; return __half22float2(h);
}
__device__ __forceinline__ u32 f2h(float2 f) {
  __half2 h = __float22half2_rn(f); return *(u32*)&h;
}

// ---------------- low pass: element bits 0..11 ----------------
// XCD pinning: b = blockIdx & 7 (round-robin blockIdx->XCD) so each batch's
// 1MB state + 0.25MB hp stays in one XCD's 4MB L2 across all 5 passes.
//  A: le = tid<<4 | j          (reg j = bits 0-3; lane0,1 = bits 4,5) <- global I/O
//  B: le = j<<8 | (l&3)<<6 | w<<4 | (l>>2)   (reg j = bits 8-11; lane0,1 = bits 6,7)
// MODE 0: gray-code hp @A, init, mixA(t0), swap, mixB(t0), swap, store @A
// MODE 1: load @A, mixA(t0), swap, mixB(t0), D @B, mixB(t1), swap, mixA(t1), store
// MODE 2: load @A, mixA(t0), swap, mixB(t0), energy @B -> atomicAdd
template <int MODE>
__global__ __launch_bounds__(256)
void k_low(const float* __restrict__ betas, const float* __restrict__ adj,
           unsigned char* __restrict__ hp8, u32* __restrict__ state,
           float* __restrict__ out, int t0) {
  __shared__ float2 swapb[4096];   // 32 KB
  __shared__ float2 ptab[160];
  __shared__ unsigned smask[NQ];
  __shared__ unsigned sfull[4];
  __shared__ int sdeg[4];
  __shared__ float wsum[4];

  const int tid = threadIdx.x;
  const int l = tid & 63, w = tid >> 6;
  const int b = blockIdx.x & 7;        // XCD-aligned batch
  const int blk6 = blockIdx.x >> 3;    // element bits 12-17
  const size_t bb = (size_t)b << NQ;
  const int lbase = blk6 << 12;
  char* L = (char*)swapb;
  const int leB = ((l & 3) << 6) | (w << 4) | ((l >> 2) & 15);
  const int bB  = leB << 3;

  const float beta0 = betas[b * NL + t0];
  float s0, c0; sincosf(beta0, &s0, &c0);
  const float tf0 = s0 / c0;
  const float c0p2 = c0 * c0, c0p4 = c0p2 * c0p2;
  const float c0p12 = c0p4 * c0p4 * c0p4;

  float tf1 = 0.f, scale = 1.f;
  if (MODE == 0) scale = 0.001953125f * c0p12;   // 1/sqrt(2^18) * cos^12
  if (MODE == 1) {
    const float beta1 = betas[b * NL + t0 + 1];
    float s1, c1; sincosf(beta1, &s1, &c1);
    tf1 = s1 / c1;
    const float c1p2 = c1 * c1, c1p4 = c1p2 * c1p2;
    scale = c0p12 * (c1p4 * c1p4 * c1p4);
  }

  if (MODE == 0) {
    if (tid < NQ) {
      unsigned m = 0;
      const float* row = adj + ((size_t)b * NQ + tid) * NQ;
      for (int vq = tid + 1; vq < NQ; ++vq)
        if (row[vq] > 0.5f) m |= 1u << (NQ - 1 - vq);
      smask[tid] = m;
    }
    if (blk6 == 0 && tid == 0) out[b] = 0.f;  // P1 completes before P5 launches
    __syncthreads();
    if (tid < 4) {  // full neighbor masks for element bits 0-3 (qubit 17-p)
      unsigned fm = smask[17 - tid];
      for (int uq = 0; uq < NQ; ++uq)
        if ((smask[uq] >> tid) & 1u) fm |= 1u << (17 - uq);
      sfull[tid] = fm; sdeg[tid] = __popc(fm);
    }
  }
  if (MODE != 2 && tid < 160) {
    float ss, cc; sincosf((float)tid, &ss, &cc);
    ptab[tid] = make_float2(cc * scale, -ss * scale);  // e^{-i h} * scale
  }

  float2 v[16];

  if (MODE == 0) {
    __syncthreads();
    // hp via gray code over element bits 0-3 (A regs)
    unsigned d = (unsigned)(lbase | (tid << 4));
    int hp = 0;
#pragma unroll
    for (int uq = 0; uq < NQ; ++uq) {
      const unsigned f = (d >> (17 - uq)) & 1u;
      hp += __popc(smask[uq] & (d ^ (0u - f)));
    }
    u64 plo = (u64)hp, phi = 0;
    int j = 0;
#pragma unroll
    for (int i = 1; i < 16; ++i) {
      const int p = __ffs(i) - 1;
      const int old = (int)((d >> p) & 1u);
      const int nb1 = __popc(sfull[p] & d);
      hp += old ? (2 * nb1 - sdeg[p]) : (sdeg[p] - 2 * nb1);
      d ^= 1u << p; j ^= 1 << p;
      if (j < 8) plo |= (u64)hp << (8 * j);
      else       phi |= (u64)hp << (8 * (j - 8));
    }
    uint4 hq;
    hq.x = (unsigned)plo; hq.y = (unsigned)(plo >> 32);
    hq.z = (unsigned)phi; hq.w = (unsigned)(phi >> 32);
    *(uint4*)(hp8 + bb + (size_t)(lbase + (tid << 4))) = hq;
#pragma unroll
    for (int jj = 0; jj < 16; ++jj) {
      const int h = (jj < 8) ? (int)((plo >> (8 * jj)) & 255)
                             : (int)((phi >> (8 * (jj - 8))) & 255);
      v[jj] = ptab[h];
    }
    mixA(v, tf0);                                 // bits 0-5
#pragma unroll
    for (int q = 0; q < 8; ++q)                   // swap A -> B
      *(float4*)(L + swz((tid << 7) + (q << 4))) =
          make_float4(v[2*q].x, v[2*q].y, v[2*q+1].x, v[2*q+1].y);
    __syncthreads();
#pragma unroll
    for (int jj = 0; jj < 16; ++jj)
      v[jj] = *(const float2*)(L + swz((jj << 11) + bB));
    mixB(v, tf0);                                 // bits 6-11
#pragma unroll
    for (int jj = 0; jj < 16; ++jj)               // swap B -> A
      *(float2*)(L + swz((jj << 11) + bB)) = v[jj];
    __syncthreads();
#pragma unroll
    for (int q = 0; q < 8; ++q) {
      const float4 f = *(const float4*)(L + swz((tid << 7) + (q << 4)));
      v[2*q]   = make_float2(f.x, f.y);
      v[2*q+1] = make_float2(f.z, f.w);
    }
    uint4* gdst = (uint4*)(state + bb + lbase + (tid << 4));
#pragma unroll
    for (int q = 0; q < 4; ++q) {
      uint4 t4;
      t4.x = f2h(v[4*q]);   t4.y = f2h(v[4*q+1]);
      t4.z = f2h(v[4*q+2]); t4.w = f2h(v[4*q+3]);
      gdst[q] = t4;
    }
    return;
  }

  // MODE 1 / 2: load @A (vectorized), mixA(t0), swap -> B, mixB(t0)
  const uint4* gsrc = (const uint4*)(state + bb + lbase + (tid << 4));
#pragma unroll
  for (int q = 0; q < 4; ++q) {
    const uint4 t4 = gsrc[q];
    v[4*q]   = h2f(t4.x); v[4*q+1] = h2f(t4.y);
    v[4*q+2] = h2f(t4.z); v[4*q+3] = h2f(t4.w);
  }
  mixA(v, tf0);                                   // bits 0-5
#pragma unroll
  for (int q = 0; q < 8; ++q)
    *(float4*)(L + swz((tid << 7) + (q << 4))) =
        make_float4(v[2*q].x, v[2*q].y, v[2*q+1].x, v[2*q+1].y);
  __syncthreads();
#pragma unroll
  for (int jj = 0; jj < 16; ++jj)
    v[jj] = *(const float2*)(L + swz((jj << 11) + bB));
  mixB(v, tf0);                                   // bits 6-11

  if (MODE == 1) {
    const unsigned char* hq = hp8 + bb + (size_t)(lbase + leB);
#pragma unroll
    for (int jj = 0; jj < 16; ++jj)
      pmul(v[jj], ptab[hq[jj << 8]]);             // diagonal @B
    mixB(v, tf1);                                 // bits 6-11
#pragma unroll
    for (int jj = 0; jj < 16; ++jj)               // swap B -> A
      *(float2*)(L + swz((jj << 11) + bB)) = v[jj];
    __syncthreads();
#pragma unroll
    for (int q = 0; q < 8; ++q) {
      const float4 f = *(const float4*)(L + swz((tid << 7) + (q << 4)));
      v[2*q]   = make_float2(f.x, f.y);
      v[2*q+1] = make_float2(f.z, f.w);
    }
    mixA(v, tf1);                                 // bits 0-5
    uint4* gdst = (uint4*)(state + bb + lbase + (tid << 4));
#pragma unroll
    for (int q = 0; q < 4; ++q) {
      uint4 t4;
      t4.x = f2h(v[4*q]);   t4.y = f2h(v[4*q+1]);
      t4.z = f2h(v[4*q+2]); t4.w = f2h(v[4*q+3]);
      gdst[q] = t4;
    }
  } else {  // MODE 2: energy @B; scale before squaring
    const unsigned char* hq = hp8 + bb + (size_t)(lbase + leB);
    float acc = 0.f;
#pragma unroll
    for (int jj = 0; jj < 16; ++jj) {
      const float h = (float)hq[jj << 8];
      const float wx = v[jj].x * c0p12, wy = v[jj].y * c0p12;
      acc = fmaf(wx * wx + wy * wy, h, acc);
    }
#pragma unroll
    for (int m = 1; m <= 32; m <<= 1) acc += __shfl_xor(acc, m, 64);
    if (l == 0) wsum[w] = acc;
    __syncthreads();
    if (tid == 0) atomicAdd(out + b, wsum[0] + wsum[1] + wsum[2] + wsum[3]);
  }
}

// ---------------- high pass: element bits 12..17 ----------------
__global__ __launch_bounds__(256)
void k_high(const float* __restrict__ betas, const unsigned char* __restrict__ hp8,
            u32* __restrict__ state, int t0) {
  __shared__ float2 swapb[4096];
  __shared__ float2 ptab[160];
  const int tid = threadIdx.x;
  const int w2 = tid >> 6, lane = tid & 63;
  const int b = blockIdx.x & 7;        // XCD-aligned batch
  const int mid = blockIdx.x >> 3;     // element bits 6-11
  const size_t bb = (size_t)b << NQ;
  const int base = (mid << 6) | lane;

  const float beta0 = betas[b * NL + t0], beta1 = betas[b * NL + t0 + 1];
  float s0, c0, s1, c1;
  sincosf(beta0, &s0, &c0); sincosf(beta1, &s1, &c1);
  const float tf0 = s0 / c0, tf1 = s1 / c1;
  const float c0p2 = c0 * c0, c1p2 = c1 * c1;
  const float scale = (c0p2 * c0p2 * c0p2) * (c1p2 * c1p2 * c1p2);  // cos^6 each
  if (tid < 160) {
    float ss, cc; sincosf((float)tid, &ss, &cc);
    ptab[tid] = make_float2(cc * scale, -ss * scale);
  }

  float2 v[16];
#pragma unroll
  for (int j = 0; j < 16; ++j)
    v[j] = h2f(state[bb + ((size_t)((w2 << 4) | j) << 12) + base]);
  tstage(v, 1, tf0); tstage(v, 2, tf0); tstage(v, 4, tf0); tstage(v, 8, tf0);
#pragma unroll
  for (int j = 0; j < 16; ++j)
    swapb[(((w2 << 4) | j) << 6) | lane] = v[j];
  __syncthreads();
#pragma unroll
  for (int j = 0; j < 16; ++j)
    v[j] = swapb[(((j << 2) | w2) << 6) | lane];
  tstage(v, 4, tf0); tstage(v, 8, tf0);           // bits 16-17
#pragma unroll
  for (int j = 0; j < 16; ++j) {
    const int h = hp8[bb + ((size_t)((j << 2) | w2) << 12) + base];
    pmul(v[j], ptab[h]);
  }
  tstage(v, 4, tf1); tstage(v, 8, tf1);           // bits 16-17
#pragma unroll
  for (int j = 0; j < 16; ++j)
    swapb[(((j << 2) | w2) << 6) | lane] = v[j];
  __syncthreads();
#pragma unroll
  for (int j = 0; j < 16; ++j)
    v[j] = swapb[(((w2 << 4) | j) << 6) | lane];
  tstage(v, 1, tf1); tstage(v, 2, tf1); tstage(v, 4, tf1); tstage(v, 8, tf1);
#pragma unroll
  for (int j = 0; j < 16; ++j)
    state[bb + ((size_t)((w2 << 4) | j) << 12) + base] = f2h(v[j]);
}

extern "C" void kernel_launch(void* const* d_in, const int* in_sizes, int n_in,
                              void* d_out, int out_size, void* d_ws, size_t ws_size,
                              hipStream_t stream) {
  const float* betas = (const float*)d_in[0];  // [8][4]
  const float* adj   = (const float*)d_in[1];  // [8][18][18]
  float* out = (float*)d_out;                  // [8] float32
  char* ws = (char*)d_ws;
  u32* state = (u32*)ws;                                              // 8 MB (half2)
  unsigned char* hp8 = (unsigned char*)(ws + (size_t)NB * QDIM * 4);  // 2 MB

  dim3 grid(NB * 64), blk(256);
  // P1: D + L0      P2: H0 D H1      P3: L1 D L2      P4: H2 D H3      P5: L3 + E
  k_low<0><<<grid, blk, 0, stream>>>(betas, adj, hp8, state, out, 0);
  k_high  <<<grid, blk, 0, stream>>>(betas, hp8, state, 0);
  k_low<1><<<grid, blk, 0, stream>>>(betas, adj, hp8, state, out, 1);
  k_high  <<<grid, blk, 0, stream>>>(betas, hp8, state, 2);
  k_low<2><<<grid, blk, 0, stream>>>(betas, adj, hp8, state, out, 3);
}

// Round 10
// 41.424 us; speedup vs baseline: 7.9615x; 1.0118x over previous
//
#include <hip/hip_runtime.h>
#include <hip/hip_fp16.h>

#define NQ 18
#define QDIM (1 << NQ)      // 262144
#define NB 8
#define NL 4

typedef unsigned u32;
typedef unsigned long long u64;

#define DPP_XOR1 0xB1   // quad_perm [1,0,3,2]  (lane bit 0)
#define DPP_XOR2 0x4E   // quad_perm [2,3,0,1]  (lane bit 1)

// tan-form butterfly: a' = a - i t b ; b' = b - i t a (cos^k deferred into ptab)
__device__ __forceinline__ void tbfly(float2& a, float2& b, float t) {
  float nax = fmaf(t, b.y, a.x);
  float nay = fmaf(-t, b.x, a.y);
  float nbx = fmaf(t, a.y, b.x);
  float nby = fmaf(-t, a.x, b.y);
  a = make_float2(nax, nay); b = make_float2(nbx, nby);
}
__device__ __forceinline__ void tstage8(float2* v, int m, float t) {
#pragma unroll
  for (int i = 0; i < 8; ++i)
    if (!(i & m)) tbfly(v[i], v[i | m], t);
}
// cross-lane butterfly via DPP (VALU pipe): new = mine + t*(other.y, -other.x)
template <int CTRL>
__device__ __forceinline__ void dppstage8(float2* v, float t) {
#pragma unroll
  for (int k = 0; k < 8; ++k) {
    float ox = __int_as_float(
        __builtin_amdgcn_mov_dpp(__float_as_int(v[k].x), CTRL, 0xF, 0xF, true));
    float oy = __int_as_float(
        __builtin_amdgcn_mov_dpp(__float_as_int(v[k].y), CTRL, 0xF, 0xF, true));
    v[k] = make_float2(fmaf(t, oy, v[k].x), fmaf(-t, ox, v[k].y));
  }
}
// cross-lane butterfly across lane bit 5 (half-wave swap)
__device__ __forceinline__ void shfl32stage8(float2* v, float t) {
#pragma unroll
  for (int k = 0; k < 8; ++k) {
    float ox = __shfl_xor(v[k].x, 32, 64);
    float oy = __shfl_xor(v[k].y, 32, 64);
    v[k] = make_float2(fmaf(t, oy, v[k].x), fmaf(-t, ox, v[k].y));
  }
}
// 6-bit mix: 3 reg bits + lane bits 0,1 (dpp) + lane bit 5 (shfl). Stage order
// is irrelevant (all RX stages commute).
__device__ __forceinline__ void mix6(float2* v, float t) {
  tstage8(v, 1, t); tstage8(v, 2, t); tstage8(v, 4, t);
  dppstage8<DPP_XOR1>(v, t); dppstage8<DPP_XOR2>(v, t);
  shfl32stage8(v, t);
}
__device__ __forceinline__ void pmul(float2& a, float2 p) {
  a = make_float2(a.x * p.x - a.y * p.y, a.x * p.y + a.y * p.x);
}
// LDS swizzle: XOR byte bits 4-6 with bits 7-9. Involution, applied both sides;
// preserves 8B/16B alignment (bits 0-3 untouched).
__device__ __forceinline__ int swz(int byte) { return byte ^ (((byte >> 7) & 7) << 4); }

// fp16 pack/unpack: one complex = half2 in a u32
__device__ __forceinline__ float2 h2f(u32 u) {
  __half2 h; *(u32*)&h = u; return __half22float2(h);
}
__device__ __forceinline__ u32 f2h(float2 f) {
  __half2 h = __float22half2_rn(f); return *(u32*)&h;
}

// ---------------- low pass: element bits 0..11 ----------------
// 512 thr, 8 elems/thread, tile 4096; b = blockIdx&7 (XCD pin), blk6 = blockIdx>>3.
//  A: le = tid<<3 | j   -> mix covers {0,1,2 (reg j), 3,4 (dpp), 8 (shfl32)}
//  B: le = j<<9 | constB -> mix covers {9,10,11 (reg j), 5,6 (dpp), 7 (shfl32)}
//  constB places lane bits (0,1,5)->elem(5,6,7), lane(2,3,4)->elem(0,1,2),
//  w(0,1)->elem(3,4), w(2)->elem 8.  Bijection over the 4096-elem tile.
// MODE 0: gray-code hp @A, init, mix6A(t0), swap, mix6B(t0), swap, store @A
// MODE 1: load @A, mix6A(t0), swap, mix6B(t0), D @B, mix6B(t1), swap, mix6A(t1), store
// MODE 2: load @A, mix6A(t0), swap, mix6B(t0), energy @B -> atomicAdd
template <int MODE>
__global__ __launch_bounds__(512)
void k_low(const float* __restrict__ betas, const float* __restrict__ adj,
           unsigned char* __restrict__ hp8, u32* __restrict__ state,
           float* __restrict__ out, int t0) {
  __shared__ float2 swapb[4096];   // 32 KB
  __shared__ float2 ptab[160];
  __shared__ unsigned smask[NQ];
  __shared__ unsigned sfull[3];
  __shared__ int sdeg[3];
  __shared__ float wsum[8];

  const int tid = threadIdx.x;
  const int l = tid & 63, w = tid >> 6;
  const int b = blockIdx.x & 7;        // XCD-aligned batch
  const int blk6 = blockIdx.x >> 3;    // element bits 12-17
  const size_t bb = (size_t)b << NQ;
  const int lbase = blk6 << 12;
  char* L = (char*)swapb;
  const int constB = ((w >> 2) << 8) | (((l >> 5) & 1) << 7) | (((l >> 1) & 1) << 6)
                   | ((l & 1) << 5) | ((w & 3) << 3) | ((l >> 2) & 7);
  const int bBbase = constB << 3;      // LDS byte base for B (add j<<12)

  const float beta0 = betas[b * NL + t0];
  float s0, c0; sincosf(beta0, &s0, &c0);
  const float tf0 = s0 / c0;
  const float c0p2 = c0 * c0, c0p4 = c0p2 * c0p2;
  const float c0p12 = c0p4 * c0p4 * c0p4;

  float tf1 = 0.f, scale = 1.f;
  if (MODE == 0) scale = 0.001953125f * c0p12;   // 1/sqrt(2^18) * cos^12
  if (MODE == 1) {
    const float beta1 = betas[b * NL + t0 + 1];
    float s1, c1; sincosf(beta1, &s1, &c1);
    tf1 = s1 / c1;
    const float c1p2 = c1 * c1, c1p4 = c1p2 * c1p2;
    scale = c0p12 * (c1p4 * c1p4 * c1p4);
  }

  if (MODE == 0) {
    if (tid < NQ) {
      unsigned m = 0;
      const float* row = adj + ((size_t)b * NQ + tid) * NQ;
      for (int vq = tid + 1; vq < NQ; ++vq)
        if (row[vq] > 0.5f) m |= 1u << (NQ - 1 - vq);
      smask[tid] = m;
    }
    if (blk6 == 0 && tid == 0) out[b] = 0.f;  // P1 completes before P5 launches
    if (tid < 160) {
      float ss, cc; sincosf((float)tid, &ss, &cc);
      ptab[tid] = make_float2(cc * scale, -ss * scale);
    }
    __syncthreads();
    if (tid < 3) {  // full neighbor masks for element bits 0-2 (qubit 17-p)
      unsigned fm = smask[17 - tid];
      for (int uq = 0; uq < NQ; ++uq)
        if ((smask[uq] >> tid) & 1u) fm |= 1u << (17 - uq);
      sfull[tid] = fm; sdeg[tid] = __popc(fm);
    }
    __syncthreads();
  } else if (MODE == 1) {
    if (tid < 160) {
      float ss, cc; sincosf((float)tid, &ss, &cc);
      ptab[tid] = make_float2(cc * scale, -ss * scale);
    }
    __syncthreads();
  }

  float2 v[8];

  if (MODE == 0) {
    // hp via gray code over element bits 0-2 (A regs)
    unsigned d = (unsigned)(lbase | (tid << 3));
    int hp = 0;
#pragma unroll
    for (int uq = 0; uq < NQ; ++uq) {
      const unsigned f = (d >> (17 - uq)) & 1u;
      hp += __popc(smask[uq] & (d ^ (0u - f)));
    }
    u64 pk = (u64)hp;
    int j = 0;
#pragma unroll
    for (int i = 1; i < 8; ++i) {
      const int p = __ffs(i) - 1;
      const int old = (int)((d >> p) & 1u);
      const int nb1 = __popc(sfull[p] & d);
      hp += old ? (2 * nb1 - sdeg[p]) : (sdeg[p] - 2 * nb1);
      d ^= 1u << p; j ^= 1 << p;
      pk |= (u64)hp << (8 * j);
    }
    *(u64*)(hp8 + bb + (size_t)(lbase + (tid << 3))) = pk;
#pragma unroll
    for (int jj = 0; jj < 8; ++jj)
      v[jj] = ptab[(int)((pk >> (8 * jj)) & 255)];
    mix6(v, tf0);                                 // A bits {0-4,8}
#pragma unroll
    for (int q = 0; q < 4; ++q)                   // swap A -> B
      *(float4*)(L + swz((tid << 6) | (q << 4))) =
          make_float4(v[2*q].x, v[2*q].y, v[2*q+1].x, v[2*q+1].y);
    __syncthreads();
#pragma unroll
    for (int jj = 0; jj < 8; ++jj)
      v[jj] = *(const float2*)(L + swz((jj << 12) + bBbase));
    mix6(v, tf0);                                 // B bits {5,6,7,9,10,11}
#pragma unroll
    for (int jj = 0; jj < 8; ++jj)                // swap B -> A
      *(float2*)(L + swz((jj << 12) + bBbase)) = v[jj];
    __syncthreads();
#pragma unroll
    for (int q = 0; q < 4; ++q) {
      const float4 f = *(const float4*)(L + swz((tid << 6) | (q << 4)));
      v[2*q]   = make_float2(f.x, f.y);
      v[2*q+1] = make_float2(f.z, f.w);
    }
    uint4* gdst = (uint4*)(state + bb + lbase + (tid << 3));
    gdst[0] = make_uint4(f2h(v[0]), f2h(v[1]), f2h(v[2]), f2h(v[3]));
    gdst[1] = make_uint4(f2h(v[4]), f2h(v[5]), f2h(v[6]), f2h(v[7]));
    return;
  }

  // MODE 1 / 2: load @A, mix6A(t0), swap -> B, mix6B(t0)
  const uint4* gsrc = (const uint4*)(state + bb + lbase + (tid << 3));
  {
    const uint4 t4a = gsrc[0], t4b = gsrc[1];
    v[0] = h2f(t4a.x); v[1] = h2f(t4a.y); v[2] = h2f(t4a.z); v[3] = h2f(t4a.w);
    v[4] = h2f(t4b.x); v[5] = h2f(t4b.y); v[6] = h2f(t4b.z); v[7] = h2f(t4b.w);
  }
  mix6(v, tf0);                                   // A bits {0-4,8}
#pragma unroll
  for (int q = 0; q < 4; ++q)
    *(float4*)(L + swz((tid << 6) | (q << 4))) =
        make_float4(v[2*q].x, v[2*q].y, v[2*q+1].x, v[2*q+1].y);
  __syncthreads();
#pragma unroll
  for (int jj = 0; jj < 8; ++jj)
    v[jj] = *(const float2*)(L + swz((jj << 12) + bBbase));
  mix6(v, tf0);                                   // B bits {5,6,7,9,10,11}

  if (MODE == 1) {
    const unsigned char* hq = hp8 + bb + (size_t)(lbase + constB);
#pragma unroll
    for (int jj = 0; jj < 8; ++jj)
      pmul(v[jj], ptab[hq[jj << 9]]);             // diagonal @B
    mix6(v, tf1);                                 // B bits
#pragma unroll
    for (int jj = 0; jj < 8; ++jj)                // swap B -> A
      *(float2*)(L + swz((jj << 12) + bBbase)) = v[jj];
    __syncthreads();
#pragma unroll
    for (int q = 0; q < 4; ++q) {
      const float4 f = *(const float4*)(L + swz((tid << 6) | (q << 4)));
      v[2*q]   = make_float2(f.x, f.y);
      v[2*q+1] = make_float2(f.z, f.w);
    }
    mix6(v, tf1);                                 // A bits
    uint4* gdst = (uint4*)(state + bb + lbase + (tid << 3));
    gdst[0] = make_uint4(f2h(v[0]), f2h(v[1]), f2h(v[2]), f2h(v[3]));
    gdst[1] = make_uint4(f2h(v[4]), f2h(v[5]), f2h(v[6]), f2h(v[7]));
  } else {  // MODE 2: energy @B; scale before squaring
    const unsigned char* hq = hp8 + bb + (size_t)(lbase + constB);
    float acc = 0.f;
#pragma unroll
    for (int jj = 0; jj < 8; ++jj) {
      const float h = (float)hq[jj << 9];
      const float wx = v[jj].x * c0p12, wy = v[jj].y * c0p12;
      acc = fmaf(wx * wx + wy * wy, h, acc);
    }
#pragma unroll
    for (int m = 1; m <= 32; m <<= 1) acc += __shfl_xor(acc, m, 64);
    if (l == 0) wsum[w] = acc;
    __syncthreads();
    if (tid == 0) {
      float s = 0.f;
#pragma unroll
      for (int i = 0; i < 8; ++i) s += wsum[i];
      atomicAdd(out + b, s);
    }
  }
}

// ---------------- high pass: element bits 12..17 ----------------
// 512 thr, 8 elems/thread, tile 4096 = 64 rows (bits 12-17) x 64 cols (bits 0-5);
// mid = blockIdx>>3 = elem bits 6-11.  col = lane -> fully coalesced 256B/wave.
// p0 rows = w<<3|j (j = bits 12-14); p1 rows = j<<3|w (j = bits 15-17). One swap
// each way, linear LDS (contiguous per-wave rows -> conflict-free).
__global__ __launch_bounds__(512)
void k_high(const float* __restrict__ betas, const unsigned char* __restrict__ hp8,
            u32* __restrict__ state, int t0) {
  __shared__ float2 swapb[4096];
  __shared__ float2 ptab[160];
  const int tid = threadIdx.x;
  const int col = tid & 63, w = tid >> 6;
  const int b = blockIdx.x & 7;        // XCD-aligned batch
  const int mid = blockIdx.x >> 3;     // element bits 6-11
  const size_t bb = (size_t)b << NQ;
  const int cbase = (mid << 6) | col;

  const float beta0 = betas[b * NL + t0], beta1 = betas[b * NL + t0 + 1];
  float s0, c0, s1, c1;
  sincosf(beta0, &s0, &c0); sincosf(beta1, &s1, &c1);
  const float tf0 = s0 / c0, tf1 = s1 / c1;
  const float c0p2 = c0 * c0, c1p2 = c1 * c1;
  const float scale = (c0p2 * c0p2 * c0p2) * (c1p2 * c1p2 * c1p2);  // cos^6 each
  if (tid < 160) {
    float ss, cc; sincosf((float)tid, &ss, &cc);
    ptab[tid] = make_float2(cc * scale, -ss * scale);
  }
  __syncthreads();

  float2 v[8];
#pragma unroll
  for (int j = 0; j < 8; ++j)
    v[j] = h2f(state[bb + ((size_t)((w << 3) | j) << 12) + cbase]);
  tstage8(v, 1, tf0); tstage8(v, 2, tf0); tstage8(v, 4, tf0);   // bits 12-14
#pragma unroll
  for (int j = 0; j < 8; ++j)                                   // swap p0 -> p1
    swapb[(((w << 3) | j) << 6) | col] = v[j];
  __syncthreads();
#pragma unroll
  for (int j = 0; j < 8; ++j)
    v[j] = swapb[(((j << 3) | w) << 6) | col];
  tstage8(v, 1, tf0); tstage8(v, 2, tf0); tstage8(v, 4, tf0);   // bits 15-17
#pragma unroll
  for (int j = 0; j < 8; ++j) {                                 // diagonal
    const int h = hp8[bb + ((size_t)((j << 3) | w) << 12) + cbase];
    pmul(v[j], ptab[h]);
  }
  tstage8(v, 1, tf1); tstage8(v, 2, tf1); tstage8(v, 4, tf1);   // bits 15-17
#pragma unroll
  for (int j = 0; j < 8; ++j)                                   // swap p1 -> p0
    swapb[(((j << 3) | w) << 6) | col] = v[j];
  __syncthreads();
#pragma unroll
  for (int j = 0; j < 8; ++j)
    v[j] = swapb[(((w << 3) | j) << 6) | col];
  tstage8(v, 1, tf1); tstage8(v, 2, tf1); tstage8(v, 4, tf1);   // bits 12-14
#pragma unroll
  for (int j = 0; j < 8; ++j)
    state[bb + ((size_t)((w << 3) | j) << 12) + cbase] = f2h(v[j]);
}

extern "C" void kernel_launch(void* const* d_in, const int* in_sizes, int n_in,
                              void* d_out, int out_size, void* d_ws, size_t ws_size,
                              hipStream_t stream) {
  const float* betas = (const float*)d_in[0];  // [8][4]
  const float* adj   = (const float*)d_in[1];  // [8][18][18]
  float* out = (float*)d_out;                  // [8] float32
  char* ws = (char*)d_ws;
  u32* state = (u32*)ws;                                              // 8 MB (half2)
  unsigned char* hp8 = (unsigned char*)(ws + (size_t)NB * QDIM * 4);  // 2 MB

  dim3 grid(NB * 64), blk(512);
  // P1: D + L0      P2: H0 D H1      P3: L1 D L2      P4: H2 D H3      P5: L3 + E
  k_low<0><<<grid, blk, 0, stream>>>(betas, adj, hp8, state, out, 0);
  k_high  <<<grid, blk, 0, stream>>>(betas, hp8, state, 0);
  k_low<1><<<grid, blk, 0, stream>>>(betas, adj, hp8, state, out, 1);
  k_high  <<<grid, blk, 0, stream>>>(betas, hp8, state, 2);
  k_low<2><<<grid, blk, 0, stream>>>(betas, adj, hp8, state, out, 3);
}